// Round 5
// baseline (473.955 us; speedup 1.0000x reference)
//
#include <hip/hip_runtime.h>

#define EMBED 1024
#define SEQ   2048
#define BATCH 4
#define HEADS 16

typedef __attribute__((ext_vector_type(8))) short short8;   // 8 bf16 in 4 VGPRs
typedef __attribute__((ext_vector_type(4))) float floatx4;

#define MFMA16(a, b, c) __builtin_amdgcn_mfma_f32_16x16x32_bf16((a), (b), (c), 0, 0, 0)
#define ATT_SCALE (0.125f * 1.44269504088896340736f)   // 1/sqrt(64) * log2(e), folded into Q

static __device__ __forceinline__ unsigned short f2bf(float f) {
  union { float f; unsigned int u; } v; v.f = f;
  unsigned int u = v.u;
  u += 0x7fffu + ((u >> 16) & 1u);       // RNE
  return (unsigned short)(u >> 16);
}

// Full-rate exp2: v_exp_f32 is ~quarter-rate (~32cy/wave); this is 7 full-rate ops.
// Cubic minimax for 2^f on [0,1), rel err ~2e-4 << bf16 ulp. Safe for |x| < 120.
static __device__ __forceinline__ float exp2_fast(float x) {
  float n = __builtin_floorf(x);
  float f = x - n;
  float p = __builtin_fmaf(f, __builtin_fmaf(f, __builtin_fmaf(f, 0.0790245f, 0.2244260f), 0.6956040f), 1.0000004f);
  union { float f; int i; } u; u.f = p;
  u.i += ((int)n) << 23;
  return u.f;
}

static __device__ __forceinline__ void async16(const unsigned short* g, unsigned short* l) {
  __builtin_amdgcn_global_load_lds(
      (const __attribute__((address_space(1))) void*)g,
      (__attribute__((address_space(3))) void*)l, 16, 0, 0);
}

// ---------------- fp32 -> bf16 elementwise (hidden) ----------------
__global__ __launch_bounds__(256) void k_cvt(const float* __restrict__ src,
                                             unsigned short* __restrict__ dst, int n8) {
  int i = blockIdx.x * 256 + threadIdx.x;
  if (i >= n8) return;
  const float4* s = (const float4*)src;
  float4 a = s[i * 2], b = s[i * 2 + 1];
  uint4 o;
  o.x = (unsigned)f2bf(a.x) | ((unsigned)f2bf(a.y) << 16);
  o.y = (unsigned)f2bf(a.z) | ((unsigned)f2bf(a.w) << 16);
  o.z = (unsigned)f2bf(b.x) | ((unsigned)f2bf(b.y) << 16);
  o.w = (unsigned)f2bf(b.z) | ((unsigned)f2bf(b.w) << 16);
  ((uint4*)dst)[i] = o;
}

// ---------------- W[k][n] -> WT[n][k] bf16 (Wq,Wk,Wv,Wp) ----------------
__global__ __launch_bounds__(256) void k_wt(const float* __restrict__ Wq, const float* __restrict__ Wk,
                                            const float* __restrict__ Wv, const float* __restrict__ Wp,
                                            unsigned short* __restrict__ WT) {
  int z = blockIdx.z;
  const float* src = (z == 0) ? Wq : (z == 1) ? Wk : (z == 2) ? Wv : Wp;
  unsigned short* dst = WT + (size_t)z * EMBED * EMBED;
  int k0 = blockIdx.x * 64, n0 = blockIdx.y * 64;
  __shared__ unsigned short tile[64][65];
  int tid = threadIdx.x;
  for (int i = tid; i < 4096; i += 256) {
    int r = i >> 6, c = i & 63;
    tile[c][r] = f2bf(src[(size_t)(k0 + r) * EMBED + n0 + c]);
  }
  __syncthreads();
  for (int i = tid; i < 4096; i += 256) {
    int r = i >> 6, c = i & 63;
    dst[(size_t)(n0 + r) * EMBED + k0 + c] = tile[r][c];
  }
}

// ---------------- QKV GEMM: C[m][n] = A[m][k]*BT[n][k] + bias, bf16 out -------
// Q columns (n0<1024) are pre-scaled by ATT_SCALE so attention needs no mul.
__global__ __launch_bounds__(256) void k_gemm_qkv(const unsigned short* __restrict__ A,
                                                  const unsigned short* __restrict__ BT,
                                                  const float* __restrict__ bq,
                                                  const float* __restrict__ bk,
                                                  const float* __restrict__ bv,
                                                  unsigned short* __restrict__ C) {
  __shared__ unsigned short Als[128 * 64];
  __shared__ unsigned short Bls[128 * 64];
  const int tid = threadIdx.x;
  const int m0 = blockIdx.x * 128, n0 = blockIdx.y * 128;
  const int w = tid >> 6, lane = tid & 63, l16 = lane & 15, quad = lane >> 4;
  const int l7 = l16 & 7;
  const int wrow = (w >> 1) * 64, wcol = (w & 1) * 64;

  floatx4 acc[4][4];
#pragma unroll
  for (int i = 0; i < 4; ++i)
#pragma unroll
    for (int j = 0; j < 4; ++j) acc[i][j] = {0.f, 0.f, 0.f, 0.f};

  const int srow = tid >> 3;
  const int scol = (((tid & 7) ^ (srow & 7)) * 8);
  const unsigned short* Ap = A + (size_t)(m0 + srow) * EMBED + scol;
  const unsigned short* Bp = BT + (size_t)(n0 + srow) * EMBED + scol;

  int ab[2], bb[2];
#pragma unroll
  for (int kc = 0; kc < 2; ++kc) {
    ab[kc] = (wrow + l16) * 64 + (((4 * kc + quad) ^ l7) << 3);
    bb[kc] = (wcol + l16) * 64 + (((4 * kc + quad) ^ l7) << 3);
  }

  for (int kt = 0; kt < 16; ++kt) {
    const int k0 = kt * 64;
#pragma unroll
    for (int i = 0; i < 4; ++i)
      async16(Ap + k0 + (size_t)i * 32 * EMBED, Als + i * 2048 + tid * 8);
#pragma unroll
    for (int i = 0; i < 4; ++i)
      async16(Bp + k0 + (size_t)i * 32 * EMBED, Bls + i * 2048 + tid * 8);
    __syncthreads();
    short8 af[4][2], bf[4][2];
#pragma unroll
    for (int mt = 0; mt < 4; ++mt)
#pragma unroll
      for (int kc = 0; kc < 2; ++kc)
        af[mt][kc] = *(const short8*)(Als + ab[kc] + mt * 1024);
#pragma unroll
    for (int nt = 0; nt < 4; ++nt)
#pragma unroll
      for (int kc = 0; kc < 2; ++kc)
        bf[nt][kc] = *(const short8*)(Bls + bb[kc] + nt * 1024);
#pragma unroll
    for (int kc = 0; kc < 2; ++kc)
#pragma unroll
      for (int mt = 0; mt < 4; ++mt)
#pragma unroll
        for (int nt = 0; nt < 4; ++nt)
          acc[mt][nt] = MFMA16(af[mt][kc], bf[nt][kc], acc[mt][nt]);
    __syncthreads();
  }

  const float* bsel = (n0 < 1024) ? bq : (n0 < 2048 ? bk : bv);
  const float scl = (n0 < 1024) ? ATT_SCALE : 1.0f;    // fold softmax scale into Q
  const int nb = n0 & 1023;
  float bias[4];
#pragma unroll
  for (int nt = 0; nt < 4; ++nt) bias[nt] = bsel[nb + wcol + nt * 16 + l16];
#pragma unroll
  for (int mt = 0; mt < 4; ++mt)
#pragma unroll
    for (int r = 0; r < 4; ++r) {
      int gm = m0 + wrow + mt * 16 + quad * 4 + r;
      size_t base = (size_t)gm * 3072 + n0 + wcol;
#pragma unroll
      for (int nt = 0; nt < 4; ++nt)
        C[base + nt * 16 + l16] = f2bf((acc[mt][nt][r] + bias[nt]) * scl);
    }
}

// ---------------- V[l][d] per (b,h) -> VT[b][h][d][l] ----------------
__global__ __launch_bounds__(256) void k_vt(const unsigned short* __restrict__ QKV,
                                            unsigned short* __restrict__ VT) {
  int lt = blockIdx.x;
  int bh = blockIdx.y;
  int b = bh >> 4, h = bh & 15;
  int l0 = lt * 64;
  __shared__ unsigned short tile[64][65];
  const unsigned short* src = QKV + (size_t)(b * SEQ) * 3072 + 2048 + h * 64;
  unsigned short* dst = VT + (size_t)bh * 64 * SEQ;
  int tid = threadIdx.x;
  for (int i = tid; i < 4096; i += 256) {
    int r = i >> 6, c = i & 63;
    tile[c][r] = src[(size_t)(l0 + r) * 3072 + c];
  }
  __syncthreads();
  for (int i = tid; i < 4096; i += 256) {
    int r = i >> 6, c = i & 63;
    dst[(size_t)r * SEQ + l0 + c] = tile[r][c];
  }
}

// ---------------- attention v5 ------------------------------------------------
// VALU-floor attack: exp2_fast (full-rate poly, ~14cy vs ~32cy v_exp) + scale
// pre-folded into Q. Occupancy: P is per-wave [16][64] ping-pong slices
// (processed per-mt), LDS = 16+16+16 = 48 KB -> 3 blocks/CU at
// __launch_bounds__(256,3). K/V double-buffered, prefetch-after-barrier.
__global__ __launch_bounds__(256, 3) void k_attn(const unsigned short* __restrict__ QKV,
                                                 const unsigned short* __restrict__ VT,
                                                 unsigned short* __restrict__ CTX) {
  const int bh = blockIdx.x, qt = blockIdx.y;
  const int b = bh >> 4, h = bh & 15;
  const int tid = threadIdx.x;
  const int w = tid >> 6, lane = tid & 63, l16 = lane & 15, quad = lane >> 4;
  const int l7 = l16 & 7, h8 = l16 >> 3;

  __shared__ unsigned short Kls[2][4096];   // [kv][d], xor-chunk swizzled
  __shared__ unsigned short Vls[2][4096];   // [d][kv], xor-chunk swizzled
  __shared__ unsigned short Pls[4][2048];   // per-wave P: 2 ping-pong [16][64] slices

  const unsigned short* Qb = QKV + (size_t)(b * SEQ + qt * 256 + w * 64) * 3072 + h * 64;
  const unsigned short* Kb = QKV + (size_t)(b * SEQ) * 3072 + 1024 + h * 64;
  const unsigned short* Vb = VT + (size_t)bh * 64 * SEQ;
  unsigned short* Pw = Pls[w];

  // zero-VALU P addressing, rotate swizzle chunk' = (chunk + row) & 7
  int pwb[8];
#pragma unroll
  for (int s = 0; s < 8; ++s)
    pwb[s] = quad * 256 + (((s + h8 + 4 * quad) & 7) << 3) + l7;
  int prb[2], kvb[2];
#pragma unroll
  for (int kc = 0; kc < 2; ++kc) {
    prb[kc] = l16 * 64 + (((4 * kc + quad + l16) & 7) << 3);
    kvb[kc] = l16 * 64 + (((4 * kc + quad) ^ l7) << 3);
  }

  short8 qf[4][2];
#pragma unroll
  for (int mt = 0; mt < 4; ++mt)
#pragma unroll
    for (int kc = 0; kc < 2; ++kc)
      qf[mt][kc] = *(const short8*)(Qb + (size_t)(mt * 16 + l16) * 3072 + kc * 32 + quad * 8);

  floatx4 o[4][4];
  float rs[4][4];
#pragma unroll
  for (int mt = 0; mt < 4; ++mt)
#pragma unroll
    for (int nt = 0; nt < 4; ++nt) { o[mt][nt] = {0.f, 0.f, 0.f, 0.f}; rs[mt][nt] = 0.f; }

  const int srow = tid >> 3;                              // 0..31
  const int scol = (((tid & 7) ^ (srow & 7)) * 8);        // swizzled source chunk

  // prologue: stage tile 0 into buffer 0
  async16(Kb + (size_t)srow * 3072 + scol, Kls[0] + tid * 8);
  async16(Kb + (size_t)(32 + srow) * 3072 + scol, Kls[0] + 2048 + tid * 8);
  async16(Vb + (size_t)srow * SEQ + scol, Vls[0] + tid * 8);
  async16(Vb + (size_t)(32 + srow) * SEQ + scol, Vls[0] + 2048 + tid * 8);

  for (int kt = 0; kt < 32; ++kt) {
    const int cur = kt & 1;
    __syncthreads();   // vmcnt(0) here drains loads issued a full tile ago
    if (kt < 31) {     // prefetch next tile into alt buffer
      const int kv1 = (kt + 1) * 64;
      async16(Kb + (size_t)(kv1 + srow) * 3072 + scol, Kls[cur ^ 1] + tid * 8);
      async16(Kb + (size_t)(kv1 + 32 + srow) * 3072 + scol, Kls[cur ^ 1] + 2048 + tid * 8);
      async16(Vb + (size_t)srow * SEQ + kv1 + scol, Vls[cur ^ 1] + tid * 8);
      async16(Vb + (size_t)(32 + srow) * SEQ + kv1 + scol, Vls[cur ^ 1] + 2048 + tid * 8);
    }
    const unsigned short* K0 = Kls[cur];
    const unsigned short* V0 = Vls[cur];

    short8 kf[4][2], vf[4][2];
#pragma unroll
    for (int nt = 0; nt < 4; ++nt)
#pragma unroll
      for (int kc = 0; kc < 2; ++kc) {
        kf[nt][kc] = *(const short8*)(K0 + kvb[kc] + nt * 1024);
        vf[nt][kc] = *(const short8*)(V0 + kvb[kc] + nt * 1024);
      }

#pragma unroll
    for (int mt = 0; mt < 4; ++mt) {
      const int sl = (mt & 1) << 10;   // ping-pong P slice
      floatx4 s[4];
#pragma unroll
      for (int nt = 0; nt < 4; ++nt) {
        floatx4 z = {0.f, 0.f, 0.f, 0.f};
        z = MFMA16(qf[mt][0], kf[nt][0], z);
        s[nt] = MFMA16(qf[mt][1], kf[nt][1], z);
      }
#pragma unroll
      for (int nt = 0; nt < 4; ++nt)
#pragma unroll
        for (int r = 0; r < 4; ++r) {
          float p = exp2_fast(s[nt][r]);
          rs[mt][r] += p;
          union { float f; unsigned u; } cv; cv.f = p;
          Pw[sl + pwb[(r + 2 * nt) & 7] + r * 64] = (unsigned short)(cv.u >> 16);
        }
      __asm__ volatile("s_waitcnt lgkmcnt(0)" ::: "memory");   // P visible (per-wave)
#pragma unroll
      for (int kc = 0; kc < 2; ++kc) {
        short8 pf = *(const short8*)(Pw + sl + prb[kc]);
#pragma unroll
        for (int nt = 0; nt < 4; ++nt)
          o[mt][nt] = MFMA16(pf, vf[nt][kc], o[mt][nt]);
      }
    }
    // no second barrier: K/V double-buffered, next barrier protects buffers
  }

  // reduce row-sums across the 16 lanes holding each row's columns
#pragma unroll
  for (int mt = 0; mt < 4; ++mt)
#pragma unroll
    for (int r = 0; r < 4; ++r) {
      float v = rs[mt][r];
#pragma unroll
      for (int off = 1; off < 16; off <<= 1) v += __shfl_xor(v, off);
      rs[mt][r] = 1.f / v;
    }

  // write ctx[b*SEQ + q][h*64 + d] bf16
#pragma unroll
  for (int mt = 0; mt < 4; ++mt)
#pragma unroll
    for (int r = 0; r < 4; ++r) {
      int gq = b * SEQ + qt * 256 + w * 64 + mt * 16 + quad * 4 + r;
      float inv = rs[mt][r];
      size_t base = (size_t)gq * EMBED + h * 64;
#pragma unroll
      for (int nt = 0; nt < 4; ++nt)
        CTX[base + nt * 16 + l16] = f2bf(o[mt][nt][r] * inv);
    }
}

// ---------------- proj GEMM + bias + residual -> fp32 x ----------------
__global__ __launch_bounds__(256) void k_gemm_proj(const unsigned short* __restrict__ A,
                                                   const unsigned short* __restrict__ BT,
                                                   const float* __restrict__ bp,
                                                   const float* __restrict__ hid,
                                                   float* __restrict__ X) {
  __shared__ unsigned short Als[128 * 64];
  __shared__ unsigned short Bls[128 * 64];
  const int tid = threadIdx.x;
  const int m0 = blockIdx.x * 128, n0 = blockIdx.y * 128;
  const int w = tid >> 6, lane = tid & 63, l16 = lane & 15, quad = lane >> 4;
  const int l7 = l16 & 7;
  const int wrow = (w >> 1) * 64, wcol = (w & 1) * 64;

  floatx4 acc[4][4];
#pragma unroll
  for (int i = 0; i < 4; ++i)
#pragma unroll
    for (int j = 0; j < 4; ++j) acc[i][j] = {0.f, 0.f, 0.f, 0.f};

  const int srow = tid >> 3;
  const int scol = (((tid & 7) ^ (srow & 7)) * 8);
  const unsigned short* Ap = A + (size_t)(m0 + srow) * EMBED + scol;
  const unsigned short* Bp = BT + (size_t)(n0 + srow) * EMBED + scol;

  int ab[2], bb[2];
#pragma unroll
  for (int kc = 0; kc < 2; ++kc) {
    ab[kc] = (wrow + l16) * 64 + (((4 * kc + quad) ^ l7) << 3);
    bb[kc] = (wcol + l16) * 64 + (((4 * kc + quad) ^ l7) << 3);
  }

  for (int kt = 0; kt < 16; ++kt) {
    const int k0 = kt * 64;
#pragma unroll
    for (int i = 0; i < 4; ++i)
      async16(Ap + k0 + (size_t)i * 32 * EMBED, Als + i * 2048 + tid * 8);
#pragma unroll
    for (int i = 0; i < 4; ++i)
      async16(Bp + k0 + (size_t)i * 32 * EMBED, Bls + i * 2048 + tid * 8);
    __syncthreads();
    short8 af[4][2], bf[4][2];
#pragma unroll
    for (int mt = 0; mt < 4; ++mt)
#pragma unroll
      for (int kc = 0; kc < 2; ++kc)
        af[mt][kc] = *(const short8*)(Als + ab[kc] + mt * 1024);
#pragma unroll
    for (int nt = 0; nt < 4; ++nt)
#pragma unroll
      for (int kc = 0; kc < 2; ++kc)
        bf[nt][kc] = *(const short8*)(Bls + bb[kc] + nt * 1024);
#pragma unroll
    for (int kc = 0; kc < 2; ++kc)
#pragma unroll
      for (int mt = 0; mt < 4; ++mt)
#pragma unroll
        for (int nt = 0; nt < 4; ++nt)
          acc[mt][nt] = MFMA16(af[mt][kc], bf[nt][kc], acc[mt][nt]);
    __syncthreads();
  }

  float bias[4];
#pragma unroll
  for (int nt = 0; nt < 4; ++nt) bias[nt] = bp[n0 + wcol + nt * 16 + l16];
#pragma unroll
  for (int mt = 0; mt < 4; ++mt)
#pragma unroll
    for (int r = 0; r < 4; ++r) {
      int gm = m0 + wrow + mt * 16 + quad * 4 + r;
      size_t base = (size_t)gm * EMBED + n0 + wcol;
#pragma unroll
      for (int nt = 0; nt < 4; ++nt) {
        size_t idx = base + nt * 16 + l16;
        X[idx] = acc[mt][nt][r] + bias[nt] + hid[idx];
      }
    }
}

// ---------------- in-place LayerNorm over E=1024, one block per row ----------------
__global__ __launch_bounds__(256) void k_ln(float* __restrict__ x,
                                            const float* __restrict__ gamma,
                                            const float* __restrict__ beta) {
  int row = blockIdx.x, tid = threadIdx.x;
  float4* rp = (float4*)(x + (size_t)row * EMBED);
  float4 v = rp[tid];
  float s = v.x + v.y + v.z + v.w;
  float q = v.x * v.x + v.y * v.y + v.z * v.z + v.w * v.w;
#pragma unroll
  for (int off = 1; off < 64; off <<= 1) {
    s += __shfl_xor(s, off);
    q += __shfl_xor(q, off);
  }
  __shared__ float ss[4], sq[4];
  int w = tid >> 6;
  if ((tid & 63) == 0) { ss[w] = s; sq[w] = q; }
  __syncthreads();
  s = ss[0] + ss[1] + ss[2] + ss[3];
  q = sq[0] + sq[1] + sq[2] + sq[3];
  float mean = s * (1.f / 1024.f);
  float var = q * (1.f / 1024.f) - mean * mean;
  float rstd = rsqrtf(var + 1e-8f);
  float4 g = ((const float4*)gamma)[tid];
  float4 be = ((const float4*)beta)[tid];
  v.x = (v.x - mean) * rstd * g.x + be.x;
  v.y = (v.y - mean) * rstd * g.y + be.y;
  v.z = (v.z - mean) * rstd * g.z + be.z;
  v.w = (v.w - mean) * rstd * g.w + be.w;
  rp[tid] = v;
}

extern "C" void kernel_launch(void* const* d_in, const int* in_sizes, int n_in,
                              void* d_out, int out_size, void* d_ws, size_t ws_size,
                              hipStream_t stream) {
  const float* hid   = (const float*)d_in[0];
  const float* Wq    = (const float*)d_in[1];
  const float* bq    = (const float*)d_in[2];
  const float* Wk    = (const float*)d_in[3];
  const float* bk    = (const float*)d_in[4];
  const float* Wv    = (const float*)d_in[5];
  const float* bv    = (const float*)d_in[6];
  const float* Wp    = (const float*)d_in[7];
  const float* bp    = (const float*)d_in[8];
  const float* gamma = (const float*)d_in[9];
  const float* beta  = (const float*)d_in[10];
  float* out = (float*)d_out;

  char* ws = (char*)d_ws;
  unsigned short* hidA = (unsigned short*)ws;                          // 16 MB  [8192][1024]
  unsigned short* WT   = (unsigned short*)(ws + (size_t)(16 << 20));   //  8 MB  [4096][1024]
  unsigned short* QKV  = (unsigned short*)(ws + (size_t)(24 << 20));   // 48 MB  [8192][3072]
  unsigned short* VT   = (unsigned short*)(ws + (size_t)(72 << 20));   // 16 MB  [64][64][2048]
  unsigned short* CTX  = (unsigned short*)(ws + (size_t)(88 << 20));   // 16 MB  [8192][1024]

  k_cvt<<<4096, 256, 0, stream>>>(hid, hidA, (BATCH * SEQ * EMBED) / 8);
  k_wt<<<dim3(16, 16, 4), 256, 0, stream>>>(Wq, Wk, Wv, Wp, WT);
  k_gemm_qkv<<<dim3(64, 24), 256, 0, stream>>>(hidA, WT, bq, bk, bv, QKV);
  k_vt<<<dim3(32, 64), 256, 0, stream>>>(QKV, VT);
  k_attn<<<dim3(64, 8), 256, 0, stream>>>(QKV, VT, CTX);
  k_gemm_proj<<<dim3(64, 8), 256, 0, stream>>>(CTX, WT + (size_t)3 * EMBED * EMBED, bp, hid, out);
  k_ln<<<8192, 256, 0, stream>>>(out, gamma, beta);
}

// Round 6
// 302.841 us; speedup vs baseline: 1.5650x; 1.5650x over previous
//
#include <hip/hip_runtime.h>

#define EMBED 1024
#define SEQ   2048
#define BATCH 4
#define HEADS 16

typedef __attribute__((ext_vector_type(8))) short short8;   // 8 bf16 in 4 VGPRs
typedef __attribute__((ext_vector_type(4))) float floatx4;

#define MFMA16(a, b, c) __builtin_amdgcn_mfma_f32_16x16x32_bf16((a), (b), (c), 0, 0, 0)
#define ATT_SCALE (0.125f * 1.44269504088896340736f)   // 1/sqrt(64) * log2(e), folded into Q

static __device__ __forceinline__ unsigned short f2bf(float f) {
  union { float f; unsigned int u; } v; v.f = f;
  unsigned int u = v.u;
  u += 0x7fffu + ((u >> 16) & 1u);       // RNE
  return (unsigned short)(u >> 16);
}

static __device__ __forceinline__ void async16(const unsigned short* g, unsigned short* l) {
  __builtin_amdgcn_global_load_lds(
      (const __attribute__((address_space(1))) void*)g,
      (__attribute__((address_space(3))) void*)l, 16, 0, 0);
}

// ---------------- fp32 -> bf16 elementwise (hidden) ----------------
__global__ __launch_bounds__(256) void k_cvt(const float* __restrict__ src,
                                             unsigned short* __restrict__ dst, int n8) {
  int i = blockIdx.x * 256 + threadIdx.x;
  if (i >= n8) return;
  const float4* s = (const float4*)src;
  float4 a = s[i * 2], b = s[i * 2 + 1];
  uint4 o;
  o.x = (unsigned)f2bf(a.x) | ((unsigned)f2bf(a.y) << 16);
  o.y = (unsigned)f2bf(a.z) | ((unsigned)f2bf(a.w) << 16);
  o.z = (unsigned)f2bf(b.x) | ((unsigned)f2bf(b.y) << 16);
  o.w = (unsigned)f2bf(b.z) | ((unsigned)f2bf(b.w) << 16);
  ((uint4*)dst)[i] = o;
}

// ---------------- W[k][n] -> WT[n][k] bf16 (Wq,Wk,Wv,Wp) ----------------
__global__ __launch_bounds__(256) void k_wt(const float* __restrict__ Wq, const float* __restrict__ Wk,
                                            const float* __restrict__ Wv, const float* __restrict__ Wp,
                                            unsigned short* __restrict__ WT) {
  int z = blockIdx.z;
  const float* src = (z == 0) ? Wq : (z == 1) ? Wk : (z == 2) ? Wv : Wp;
  unsigned short* dst = WT + (size_t)z * EMBED * EMBED;
  int k0 = blockIdx.x * 64, n0 = blockIdx.y * 64;
  __shared__ unsigned short tile[64][65];
  int tid = threadIdx.x;
  for (int i = tid; i < 4096; i += 256) {
    int r = i >> 6, c = i & 63;
    tile[c][r] = f2bf(src[(size_t)(k0 + r) * EMBED + n0 + c]);
  }
  __syncthreads();
  for (int i = tid; i < 4096; i += 256) {
    int r = i >> 6, c = i & 63;
    dst[(size_t)(n0 + r) * EMBED + k0 + c] = tile[r][c];
  }
}

// ---------------- QKV GEMM: C[m][n] = A[m][k]*BT[n][k] + bias, bf16 out -------
// Q columns (n0<1024) pre-scaled by ATT_SCALE so attention needs no mul.
__global__ __launch_bounds__(256) void k_gemm_qkv(const unsigned short* __restrict__ A,
                                                  const unsigned short* __restrict__ BT,
                                                  const float* __restrict__ bq,
                                                  const float* __restrict__ bk,
                                                  const float* __restrict__ bv,
                                                  unsigned short* __restrict__ C) {
  __shared__ unsigned short Als[128 * 64];
  __shared__ unsigned short Bls[128 * 64];
  const int tid = threadIdx.x;
  const int m0 = blockIdx.x * 128, n0 = blockIdx.y * 128;
  const int w = tid >> 6, lane = tid & 63, l16 = lane & 15, quad = lane >> 4;
  const int l7 = l16 & 7;
  const int wrow = (w >> 1) * 64, wcol = (w & 1) * 64;

  floatx4 acc[4][4];
#pragma unroll
  for (int i = 0; i < 4; ++i)
#pragma unroll
    for (int j = 0; j < 4; ++j) acc[i][j] = {0.f, 0.f, 0.f, 0.f};

  const int srow = tid >> 3;
  const int scol = (((tid & 7) ^ (srow & 7)) * 8);
  const unsigned short* Ap = A + (size_t)(m0 + srow) * EMBED + scol;
  const unsigned short* Bp = BT + (size_t)(n0 + srow) * EMBED + scol;

  int ab[2], bb[2];
#pragma unroll
  for (int kc = 0; kc < 2; ++kc) {
    ab[kc] = (wrow + l16) * 64 + (((4 * kc + quad) ^ l7) << 3);
    bb[kc] = (wcol + l16) * 64 + (((4 * kc + quad) ^ l7) << 3);
  }

  for (int kt = 0; kt < 16; ++kt) {
    const int k0 = kt * 64;
#pragma unroll
    for (int i = 0; i < 4; ++i)
      async16(Ap + k0 + (size_t)i * 32 * EMBED, Als + i * 2048 + tid * 8);
#pragma unroll
    for (int i = 0; i < 4; ++i)
      async16(Bp + k0 + (size_t)i * 32 * EMBED, Bls + i * 2048 + tid * 8);
    __syncthreads();
    short8 af[4][2], bf[4][2];
#pragma unroll
    for (int mt = 0; mt < 4; ++mt)
#pragma unroll
      for (int kc = 0; kc < 2; ++kc)
        af[mt][kc] = *(const short8*)(Als + ab[kc] + mt * 1024);
#pragma unroll
    for (int nt = 0; nt < 4; ++nt)
#pragma unroll
      for (int kc = 0; kc < 2; ++kc)
        bf[nt][kc] = *(const short8*)(Bls + bb[kc] + nt * 1024);
#pragma unroll
    for (int kc = 0; kc < 2; ++kc)
#pragma unroll
      for (int mt = 0; mt < 4; ++mt)
#pragma unroll
        for (int nt = 0; nt < 4; ++nt)
          acc[mt][nt] = MFMA16(af[mt][kc], bf[nt][kc], acc[mt][nt]);
    __syncthreads();
  }

  const float* bsel = (n0 < 1024) ? bq : (n0 < 2048 ? bk : bv);
  const float scl = (n0 < 1024) ? ATT_SCALE : 1.0f;
  const int nb = n0 & 1023;
  float bias[4];
#pragma unroll
  for (int nt = 0; nt < 4; ++nt) bias[nt] = bsel[nb + wcol + nt * 16 + l16];
#pragma unroll
  for (int mt = 0; mt < 4; ++mt)
#pragma unroll
    for (int r = 0; r < 4; ++r) {
      int gm = m0 + wrow + mt * 16 + quad * 4 + r;
      size_t base = (size_t)gm * 3072 + n0 + wcol;
#pragma unroll
      for (int nt = 0; nt < 4; ++nt)
        C[base + nt * 16 + l16] = f2bf((acc[mt][nt][r] + bias[nt]) * scl);
    }
}

// ---------------- V[l][d] per (b,h) -> VT[b][h][d][l] ----------------
__global__ __launch_bounds__(256) void k_vt(const unsigned short* __restrict__ QKV,
                                            unsigned short* __restrict__ VT) {
  int lt = blockIdx.x;
  int bh = blockIdx.y;
  int b = bh >> 4, h = bh & 15;
  int l0 = lt * 64;
  __shared__ unsigned short tile[64][65];
  const unsigned short* src = QKV + (size_t)(b * SEQ) * 3072 + 2048 + h * 64;
  unsigned short* dst = VT + (size_t)bh * 64 * SEQ;
  int tid = threadIdx.x;
  for (int i = tid; i < 4096; i += 256) {
    int r = i >> 6, c = i & 63;
    tile[c][r] = src[(size_t)(l0 + r) * 3072 + c];
  }
  __syncthreads();
  for (int i = tid; i < 4096; i += 256) {
    int r = i >> 6, c = i & 63;
    dst[(size_t)r * SEQ + l0 + c] = tile[r][c];
  }
}

// ---------------- attention v6 = R2 kernel (measured optimum, 136us) ----------
// + XCD swizzle: grid(64,8), bh on x -> the 8 q-blocks of one (b,h) share an XCD
//   (validated: FETCH 139 -> ~35 MB in R3/R4).
// + scale pre-folded into Q; exp2 via bare v_exp_f32 builtin.
// Single-buffered K/V, 2 barriers/kt, full 64x64 P per wave, xor-chunk swizzle,
// __launch_bounds__(256,2) -- NO min-waves=3 (R5 spilled to scratch: 1 GB writes).
__global__ __launch_bounds__(256, 2) void k_attn(const unsigned short* __restrict__ QKV,
                                                 const unsigned short* __restrict__ VT,
                                                 unsigned short* __restrict__ CTX) {
  const int bh = blockIdx.x, qt = blockIdx.y;
  const int b = bh >> 4, h = bh & 15;
  const int tid = threadIdx.x;
  const int w = tid >> 6, lane = tid & 63, l16 = lane & 15, quad = lane >> 4;

  __shared__ unsigned short Kls[64 * 64];       // [kv][d]  swizzled
  __shared__ unsigned short Vls[64 * 64];       // [d][kv]  swizzled
  __shared__ unsigned short Pls[4][64 * 64];    // per-wave P [q][kv]  swizzled

  const unsigned short* Qb = QKV + (size_t)(b * SEQ + qt * 256 + w * 64) * 3072 + h * 64;
  const unsigned short* Kb = QKV + (size_t)(b * SEQ) * 3072 + 1024 + h * 64;
  const unsigned short* Vb = VT + (size_t)bh * 64 * SEQ;
  unsigned short* Pw = Pls[w];

  // Q fragments: wave owns 64 q-rows (Q pre-scaled by ATT_SCALE)
  short8 qf[4][2];
#pragma unroll
  for (int mt = 0; mt < 4; ++mt)
#pragma unroll
    for (int kc = 0; kc < 2; ++kc)
      qf[mt][kc] = *(const short8*)(Qb + (size_t)(mt * 16 + l16) * 3072 + kc * 32 + quad * 8);

  floatx4 o[4][4];
  float rs[4][4];
#pragma unroll
  for (int mt = 0; mt < 4; ++mt)
#pragma unroll
    for (int nt = 0; nt < 4; ++nt) { o[mt][nt] = {0.f, 0.f, 0.f, 0.f}; rs[mt][nt] = 0.f; }

  const int srow = tid >> 3;                              // 0..31
  const int scol = (((tid & 7) ^ (srow & 7)) * 8);        // swizzled source chunk

  for (int kt = 0; kt < 32; ++kt) {
    const int kv0 = kt * 64;
    async16(Kb + (size_t)(kv0 + srow) * 3072 + scol, Kls + tid * 8);
    async16(Kb + (size_t)(kv0 + 32 + srow) * 3072 + scol, Kls + 2048 + tid * 8);
    async16(Vb + (size_t)srow * SEQ + kv0 + scol, Vls + tid * 8);
    async16(Vb + (size_t)(32 + srow) * SEQ + kv0 + scol, Vls + 2048 + tid * 8);
    __syncthreads();

    // S = Q K^T
    short8 kf[4][2];
#pragma unroll
    for (int nt = 0; nt < 4; ++nt)
#pragma unroll
      for (int kc = 0; kc < 2; ++kc) {
        int row = nt * 16 + l16;
        kf[nt][kc] = *(const short8*)(Kls + row * 64 + (((kc * 4 + quad) ^ (row & 7)) * 8));
      }

#pragma unroll
    for (int mt = 0; mt < 4; ++mt) {
      floatx4 s[4];
#pragma unroll
      for (int nt = 0; nt < 4; ++nt) {
        floatx4 z = {0.f, 0.f, 0.f, 0.f};
        z = MFMA16(qf[mt][0], kf[nt][0], z);
        s[nt] = MFMA16(qf[mt][1], kf[nt][1], z);
      }
      // p = exp2(s); accumulate fp32 row-sums; truncate-to-bf16 into P
#pragma unroll
      for (int nt = 0; nt < 4; ++nt)
#pragma unroll
        for (int r = 0; r < 4; ++r) {
          float p = __builtin_amdgcn_exp2f(s[nt][r]);
          rs[mt][r] += p;
          int row = mt * 16 + quad * 4 + r;
          int col = nt * 16 + l16;
          union { float f; unsigned u; } cv; cv.f = p;
          Pw[row * 64 + (((col >> 3) ^ (row & 7)) * 8) + (col & 7)] = (unsigned short)(cv.u >> 16);
        }
    }

    // per-wave P: LDS pipe is in-order per wave; fence + stop reordering
    __asm__ volatile("s_waitcnt lgkmcnt(0)" ::: "memory");

    // O += P V
    short8 vf[4][2];
#pragma unroll
    for (int nt = 0; nt < 4; ++nt)
#pragma unroll
      for (int kc = 0; kc < 2; ++kc) {
        int row = nt * 16 + l16;
        vf[nt][kc] = *(const short8*)(Vls + row * 64 + (((kc * 4 + quad) ^ (row & 7)) * 8));
      }
#pragma unroll
    for (int kc = 0; kc < 2; ++kc)
#pragma unroll
      for (int mt = 0; mt < 4; ++mt) {
        int row = mt * 16 + l16;
        short8 pf = *(const short8*)(Pw + row * 64 + (((kc * 4 + quad) ^ (row & 7)) * 8));
#pragma unroll
        for (int nt = 0; nt < 4; ++nt)
          o[mt][nt] = MFMA16(pf, vf[nt][kc], o[mt][nt]);
      }
    __syncthreads();   // protect K/V LDS before next staging
  }

  // reduce row-sums across the 16 lanes holding each row's columns
#pragma unroll
  for (int mt = 0; mt < 4; ++mt)
#pragma unroll
    for (int r = 0; r < 4; ++r) {
      float v = rs[mt][r];
#pragma unroll
      for (int off = 1; off < 16; off <<= 1) v += __shfl_xor(v, off);
      rs[mt][r] = 1.f / v;
    }

  // write ctx[b*SEQ + q][h*64 + d] bf16
#pragma unroll
  for (int mt = 0; mt < 4; ++mt)
#pragma unroll
    for (int r = 0; r < 4; ++r) {
      int gq = b * SEQ + qt * 256 + w * 64 + mt * 16 + quad * 4 + r;
      float inv = rs[mt][r];
      size_t base = (size_t)gq * EMBED + h * 64;
#pragma unroll
      for (int nt = 0; nt < 4; ++nt)
        CTX[base + nt * 16 + l16] = f2bf(o[mt][nt][r] * inv);
    }
}

// ---------------- proj GEMM + bias + residual -> fp32 x ----------------
__global__ __launch_bounds__(256) void k_gemm_proj(const unsigned short* __restrict__ A,
                                                   const unsigned short* __restrict__ BT,
                                                   const float* __restrict__ bp,
                                                   const float* __restrict__ hid,
                                                   float* __restrict__ X) {
  __shared__ unsigned short Als[128 * 64];
  __shared__ unsigned short Bls[128 * 64];
  const int tid = threadIdx.x;
  const int m0 = blockIdx.x * 128, n0 = blockIdx.y * 128;
  const int w = tid >> 6, lane = tid & 63, l16 = lane & 15, quad = lane >> 4;
  const int l7 = l16 & 7;
  const int wrow = (w >> 1) * 64, wcol = (w & 1) * 64;

  floatx4 acc[4][4];
#pragma unroll
  for (int i = 0; i < 4; ++i)
#pragma unroll
    for (int j = 0; j < 4; ++j) acc[i][j] = {0.f, 0.f, 0.f, 0.f};

  const int srow = tid >> 3;
  const int scol = (((tid & 7) ^ (srow & 7)) * 8);
  const unsigned short* Ap = A + (size_t)(m0 + srow) * EMBED + scol;
  const unsigned short* Bp = BT + (size_t)(n0 + srow) * EMBED + scol;

  int ab[2], bb[2];
#pragma unroll
  for (int kc = 0; kc < 2; ++kc) {
    ab[kc] = (wrow + l16) * 64 + (((4 * kc + quad) ^ l7) << 3);
    bb[kc] = (wcol + l16) * 64 + (((4 * kc + quad) ^ l7) << 3);
  }

  for (int kt = 0; kt < 16; ++kt) {
    const int k0 = kt * 64;
#pragma unroll
    for (int i = 0; i < 4; ++i)
      async16(Ap + k0 + (size_t)i * 32 * EMBED, Als + i * 2048 + tid * 8);
#pragma unroll
    for (int i = 0; i < 4; ++i)
      async16(Bp + k0 + (size_t)i * 32 * EMBED, Bls + i * 2048 + tid * 8);
    __syncthreads();
    short8 af[4][2], bf[4][2];
#pragma unroll
    for (int mt = 0; mt < 4; ++mt)
#pragma unroll
      for (int kc = 0; kc < 2; ++kc)
        af[mt][kc] = *(const short8*)(Als + ab[kc] + mt * 1024);
#pragma unroll
    for (int nt = 0; nt < 4; ++nt)
#pragma unroll
      for (int kc = 0; kc < 2; ++kc)
        bf[nt][kc] = *(const short8*)(Bls + bb[kc] + nt * 1024);
#pragma unroll
    for (int kc = 0; kc < 2; ++kc)
#pragma unroll
      for (int mt = 0; mt < 4; ++mt)
#pragma unroll
        for (int nt = 0; nt < 4; ++nt)
          acc[mt][nt] = MFMA16(af[mt][kc], bf[nt][kc], acc[mt][nt]);
    __syncthreads();
  }

  float bias[4];
#pragma unroll
  for (int nt = 0; nt < 4; ++nt) bias[nt] = bp[n0 + wcol + nt * 16 + l16];
#pragma unroll
  for (int mt = 0; mt < 4; ++mt)
#pragma unroll
    for (int r = 0; r < 4; ++r) {
      int gm = m0 + wrow + mt * 16 + quad * 4 + r;
      size_t base = (size_t)gm * EMBED + n0 + wcol;
#pragma unroll
      for (int nt = 0; nt < 4; ++nt) {
        size_t idx = base + nt * 16 + l16;
        X[idx] = acc[mt][nt][r] + bias[nt] + hid[idx];
      }
    }
}

// ---------------- in-place LayerNorm over E=1024, one block per row ----------------
__global__ __launch_bounds__(256) void k_ln(float* __restrict__ x,
                                            const float* __restrict__ gamma,
                                            const float* __restrict__ beta) {
  int row = blockIdx.x, tid = threadIdx.x;
  float4* rp = (float4*)(x + (size_t)row * EMBED);
  float4 v = rp[tid];
  float s = v.x + v.y + v.z + v.w;
  float q = v.x * v.x + v.y * v.y + v.z * v.z + v.w * v.w;
#pragma unroll
  for (int off = 1; off < 64; off <<= 1) {
    s += __shfl_xor(s, off);
    q += __shfl_xor(q, off);
  }
  __shared__ float ss[4], sq[4];
  int w = tid >> 6;
  if ((tid & 63) == 0) { ss[w] = s; sq[w] = q; }
  __syncthreads();
  s = ss[0] + ss[1] + ss[2] + ss[3];
  q = sq[0] + sq[1] + sq[2] + sq[3];
  float mean = s * (1.f / 1024.f);
  float var = q * (1.f / 1024.f) - mean * mean;
  float rstd = rsqrtf(var + 1e-8f);
  float4 g = ((const float4*)gamma)[tid];
  float4 be = ((const float4*)beta)[tid];
  v.x = (v.x - mean) * rstd * g.x + be.x;
  v.y = (v.y - mean) * rstd * g.y + be.y;
  v.z = (v.z - mean) * rstd * g.z + be.z;
  v.w = (v.w - mean) * rstd * g.w + be.w;
  rp[tid] = v;
}

extern "C" void kernel_launch(void* const* d_in, const int* in_sizes, int n_in,
                              void* d_out, int out_size, void* d_ws, size_t ws_size,
                              hipStream_t stream) {
  const float* hid   = (const float*)d_in[0];
  const float* Wq    = (const float*)d_in[1];
  const float* bq    = (const float*)d_in[2];
  const float* Wk    = (const float*)d_in[3];
  const float* bk    = (const float*)d_in[4];
  const float* Wv    = (const float*)d_in[5];
  const float* bv    = (const float*)d_in[6];
  const float* Wp    = (const float*)d_in[7];
  const float* bp    = (const float*)d_in[8];
  const float* gamma = (const float*)d_in[9];
  const float* beta  = (const float*)d_in[10];
  float* out = (float*)d_out;

  char* ws = (char*)d_ws;
  unsigned short* hidA = (unsigned short*)ws;                          // 16 MB  [8192][1024]
  unsigned short* WT   = (unsigned short*)(ws + (size_t)(16 << 20));   //  8 MB  [4096][1024]
  unsigned short* QKV  = (unsigned short*)(ws + (size_t)(24 << 20));   // 48 MB  [8192][3072]
  unsigned short* VT   = (unsigned short*)(ws + (size_t)(72 << 20));   // 16 MB  [64][64][2048]
  unsigned short* CTX  = (unsigned short*)(ws + (size_t)(88 << 20));   // 16 MB  [8192][1024]

  k_cvt<<<4096, 256, 0, stream>>>(hid, hidA, (BATCH * SEQ * EMBED) / 8);
  k_wt<<<dim3(16, 16, 4), 256, 0, stream>>>(Wq, Wk, Wv, Wp, WT);
  k_gemm_qkv<<<dim3(64, 24), 256, 0, stream>>>(hidA, WT, bq, bk, bv, QKV);
  k_vt<<<dim3(32, 64), 256, 0, stream>>>(QKV, VT);
  k_attn<<<dim3(64, 8), 256, 0, stream>>>(QKV, VT, CTX);
  k_gemm_proj<<<dim3(64, 8), 256, 0, stream>>>(CTX, WT + (size_t)3 * EMBED * EMBED, bp, hid, out);
  k_ln<<<8192, 256, 0, stream>>>(out, gamma, beta);
}